// Round 13
// baseline (28.033 us; speedup 1.0000x reference)
//
#include <hip/hip_runtime.h>
#include <hip/hip_bf16.h>
#include <cstdint>

// VQ-VAE vector quantize: N=65536 vectors, D=64, K=512 codes.
// d_in[0]: inputs fp32 [65536,64], d_in[1]: embeddings fp32 [512,64]
// d_out: [0]=loss, [1..4194304]=latent (gathered fp32 embeddings)
//
// R13: stage-once / barrier-once. 512 blocks x 512 threads (128 rows/block,
// 16 rows/wave). Full 66 KB codebook staged into LDS once (global_load_lds),
// ONE __syncthreads, then 8 waves stream the 32 col-tiles freely (staggered
// start). 2 blocks/CU via LDS, VGPRs unconstrained (R7 lesson). Loss from
// winning packed distance; separate 1-block deterministic reduce.

typedef __attribute__((ext_vector_type(8))) short bf16x8;
typedef __attribute__((ext_vector_type(4))) float f32x4;

__device__ __forceinline__ short f2bf(float f) {
    uint32_t u = __builtin_bit_cast(uint32_t, f);
    u += 0x7FFFu + ((u >> 16) & 1u);   // round-to-nearest-even
    return (short)(u >> 16);
}

// ws layout (bytes):
//  [0, 65536)     : B fragments bf16(-e), [ct(32)][ks(2)][lane(64)] x 16B
//  [65536, 67584) : ee_t[512] fp32 = 0.5*||e_k||^2, TRANSPOSED [cb(16)][ct(32)]
//  [67584, 69632) : partials[512] fp32
#define WS_EE   65536
#define WS_PART 67584

// ---------------- Kernel 1: setup (16 blocks x 256) ----------------
__global__ __launch_bounds__(256)
void vq_setup(const float* __restrict__ emb, char* __restrict__ ws) {
    const int tid = threadIdx.x, bid = blockIdx.x;
    bf16x8* bfrag = (bf16x8*)ws;
    float* eet = (float*)(ws + WS_EE);

    const int s = bid * 256 + tid;
    const int ct = s >> 7, ks = (s >> 6) & 1, ln = s & 63;
    const int code = (ct << 4) | (ln & 15);
    const int d0 = ks * 32 + ((ln >> 4) << 3);
    const float* src = emb + code * 64 + d0;
    float4 v0 = *(const float4*)src;
    float4 v1 = *(const float4*)(src + 4);
    bf16x8 b;
    b[0] = f2bf(-v0.x); b[1] = f2bf(-v0.y); b[2] = f2bf(-v0.z); b[3] = f2bf(-v0.w);
    b[4] = f2bf(-v1.x); b[5] = f2bf(-v1.y); b[6] = f2bf(-v1.z); b[7] = f2bf(-v1.w);
    bfrag[s] = b;

    if (tid < 32) {
        const int c = bid * 32 + tid;
        const float4* e4 = (const float4*)(emb + c * 64);
        float acc = 0.f;
        #pragma unroll
        for (int q = 0; q < 16; ++q) {
            float4 v = e4[q];
            acc = fmaf(v.x, v.x, fmaf(v.y, v.y, fmaf(v.z, v.z, fmaf(v.w, v.w, acc))));
        }
        eet[(c & 15) * 32 + (c >> 4)] = 0.5f * acc;   // transposed, pre-halved
    }
}

// ---------------- Kernel 2: main (512 blocks x 512) ----------------
__global__ __launch_bounds__(512)
void vq_main(const float* __restrict__ flat, const float* __restrict__ emb,
             char* __restrict__ ws, float* __restrict__ out) {
    __shared__ char lds[67584];   // 64 KB bfrag + 2 KB ee_t
    __shared__ float red[8];

    bf16x8* lbuf = (bf16x8*)lds;
    const float* eel = (const float*)(lds + WS_EE);

    const int tid = threadIdx.x, bid = blockIdx.x;
    const int lane = tid & 63, wid = tid >> 6;
    const int cb = lane & 15, g = lane >> 4;
    const int rb = bid * 128 + wid * 16;   // wave's 16 rows
    const char* wsg = (const char*)ws;

    // ---- A loads: 1 M-tile x 2 k-steps x 2 float4 (HBM) ----
    const float* asrc = flat + (long)(rb + cb) * 64 + (g << 3);
    float4 ar00 = *(const float4*)asrc;
    float4 ar01 = *(const float4*)(asrc + 4);
    float4 ar10 = *(const float4*)(asrc + 32);
    float4 ar11 = *(const float4*)(asrc + 36);

    // ---- stage codebook + norms ONCE (66 KB, global_load_lds width 16) ----
    {
        #pragma unroll
        for (int k = 0; k < 8; ++k) {
            const int off = (k * 512 + tid) * 16;
            __builtin_amdgcn_global_load_lds(
                (const __attribute__((address_space(1))) void*)(wsg + off),
                (__attribute__((address_space(3))) void*)(lds + off), 16, 0, 0);
        }
        if (tid < 128) {
            const int off = WS_EE + tid * 16;
            __builtin_amdgcn_global_load_lds(
                (const __attribute__((address_space(1))) void*)(wsg + off),
                (__attribute__((address_space(3))) void*)(lds + off), 16, 0, 0);
        }
    }

    // ---- ||x||^2 partial + bf16 convert (overlaps staging) ----
    float xx = 0.f;
    {
        float4 v;
        v = ar00; xx = fmaf(v.x, v.x, fmaf(v.y, v.y, fmaf(v.z, v.z, fmaf(v.w, v.w, xx))));
        v = ar01; xx = fmaf(v.x, v.x, fmaf(v.y, v.y, fmaf(v.z, v.z, fmaf(v.w, v.w, xx))));
        v = ar10; xx = fmaf(v.x, v.x, fmaf(v.y, v.y, fmaf(v.z, v.z, fmaf(v.w, v.w, xx))));
        v = ar11; xx = fmaf(v.x, v.x, fmaf(v.y, v.y, fmaf(v.z, v.z, fmaf(v.w, v.w, xx))));
    }
    bf16x8 a0, a1;
    a0[0] = f2bf(ar00.x); a0[1] = f2bf(ar00.y); a0[2] = f2bf(ar00.z); a0[3] = f2bf(ar00.w);
    a0[4] = f2bf(ar01.x); a0[5] = f2bf(ar01.y); a0[6] = f2bf(ar01.z); a0[7] = f2bf(ar01.w);
    a1[0] = f2bf(ar10.x); a1[1] = f2bf(ar10.y); a1[2] = f2bf(ar10.z); a1[3] = f2bf(ar10.w);
    a1[4] = f2bf(ar11.x); a1[5] = f2bf(ar11.y); a1[6] = f2bf(ar11.z); a1[7] = f2bf(ar11.w);

    __syncthreads();   // the ONLY barrier: staging complete

    // ---- 32 col-tiles, staggered start per wave, no further syncs ----
    float pm[4];
    #pragma unroll
    for (int i = 0; i < 4; ++i) pm[i] = __builtin_bit_cast(float, 0x7F800000u);

    #pragma unroll 8
    for (int i = 0; i < 32; ++i) {
        const int ct = ((wid << 2) + i) & 31;
        bf16x8 b0 = lbuf[ct * 128 + lane];
        bf16x8 b1 = lbuf[ct * 128 + 64 + lane];
        const float h = eel[cb * 32 + ct];     // 0.5*||e||^2 (pre-halved)
        const int colv = (ct << 4) | cb;
        f32x4 acc = {h, h, h, h};              // 0.5||e||^2 - x.e   (B = -e)
        acc = __builtin_amdgcn_mfma_f32_16x16x32_bf16(a0, b0, acc, 0, 0, 0);
        acc = __builtin_amdgcn_mfma_f32_16x16x32_bf16(a1, b1, acc, 0, 0, 0);
        #pragma unroll
        for (int j = 0; j < 4; ++j) {
            uint32_t dp = (__builtin_bit_cast(uint32_t, acc[j]) & 0xFFFFFE00u) | (uint32_t)colv;
            pm[j] = fminf(pm[j], __builtin_bit_cast(float, dp));
        }
    }

    // ---- butterfly min over the 16 column-class lanes ----
    #pragma unroll
    for (int m = 1; m < 16; m <<= 1) {
        #pragma unroll
        for (int i = 0; i < 4; ++i)
            pm[i] = fminf(pm[i], __shfl_xor(pm[i], m, 64));
    }
    // group g's lanes now hold winners of rows rb + g*4 + j

    // ---- loss partial: sum_rows( ||x||^2 + 2*unpack(pm_min) ) ----
    float t = xx;
    if (cb == 0) {
        #pragma unroll
        for (int j = 0; j < 4; ++j) {
            float v = __builtin_bit_cast(float, __builtin_bit_cast(uint32_t, pm[j]) & 0xFFFFFE00u);
            t = fmaf(2.f, v, t);
        }
    }
    #pragma unroll
    for (int m = 32; m; m >>= 1) t += __shfl_down(t, m, 64);
    if (lane == 0) red[wid] = t;

    // ---- epilogue: shuffle-free group-parallel gather + store ----
    float* ob = out + 1 + (long)rb * 64;
    const int l4 = cb * 4;
    #pragma unroll
    for (int j = 0; j < 4; ++j) {
        const int ix = (int)(__builtin_bit_cast(uint32_t, pm[j]) & 0x1FFu);
        float4 e = *(const float4*)(emb + ix * 64 + l4);
        const int ro = (g * 4 + j) * 64 + l4;
        ob[ro] = e.x; ob[ro + 1] = e.y; ob[ro + 2] = e.z; ob[ro + 3] = e.w;
    }

    __syncthreads();
    if (tid == 0) {
        float s = 0.f;
        #pragma unroll
        for (int i = 0; i < 8; ++i) s += red[i];
        ((float*)(ws + WS_PART))[bid] = s;
    }
}

// ---------------- Kernel 3: deterministic final reduce (1 block) ----------------
__global__ __launch_bounds__(256)
void vq_loss(const float* __restrict__ partials, float* __restrict__ out) {
    __shared__ float red[4];
    const int tid = threadIdx.x;
    float acc = partials[tid] + partials[tid + 256];
    #pragma unroll
    for (int m = 32; m; m >>= 1) acc += __shfl_down(acc, m, 64);
    if ((tid & 63) == 0) red[tid >> 6] = acc;
    __syncthreads();
    // loss = 0.25*e_loss + q_loss = 1.25 * mse (forward)
    if (tid == 0) out[0] = 1.25f * (red[0] + red[1] + red[2] + red[3]) / 4194304.0f;
}

extern "C" void kernel_launch(void* const* d_in, const int* in_sizes, int n_in,
                              void* d_out, int out_size, void* d_ws, size_t ws_size,
                              hipStream_t stream) {
    const float* flat = (const float*)d_in[0];   // [65536,64]
    const float* emb  = (const float*)d_in[1];   // [512,64]
    float* out = (float*)d_out;
    char* ws = (char*)d_ws;

    vq_setup<<<16, 256, 0, stream>>>(emb, ws);
    vq_main<<<512, 512, 0, stream>>>(flat, emb, ws, out);
    vq_loss<<<1, 256, 0, stream>>>((const float*)(ws + WS_PART), out);
}